// Round 1
// baseline (435.022 us; speedup 1.0000x reference)
//
#include <hip/hip_runtime.h>

#define DEV_INLINE __device__ __forceinline__

DEV_INLINE float lane_bcast(float v, int srcLane) {
  return __int_as_float(__builtin_amdgcn_readlane(__float_as_int(v), srcLane));
}

// One wave per row. Weights staged in LDS once per block.
// Layer A: [KIN]->[128] + relu, Layer B: [128]->[64].
// Lane l accumulates hidden units l and l+64, and output unit l.
template<int KIN, bool RESID>
__global__ __launch_bounds__(256)
void mlp2_kernel(const float* __restrict__ src0,   // [rows][64]
                 const float* __restrict__ src1,   // [rows][64] or null (KIN==64)
                 const float* __restrict__ Wa,     // [KIN][128]
                 const float* __restrict__ ba,     // [128]
                 const float* __restrict__ Wb,     // [128][64]
                 const float* __restrict__ bb,     // [64]
                 float* __restrict__ out,          // [rows][64]
                 int rowsPerBlock)
{
  __shared__ float Wa_s[KIN * 128];
  __shared__ float Wb_s[128 * 64];
  {
    const float4* Wa4 = (const float4*)Wa;
    float4* Wa_s4 = (float4*)Wa_s;
    for (int i = threadIdx.x; i < KIN * 32; i += 256) Wa_s4[i] = Wa4[i];
    const float4* Wb4 = (const float4*)Wb;
    float4* Wb_s4 = (float4*)Wb_s;
    for (int i = threadIdx.x; i < 128 * 16; i += 256) Wb_s4[i] = Wb4[i];
  }
  __syncthreads();

  const int lane = threadIdx.x & 63;
  const int wave = threadIdx.x >> 6;
  const float ba0 = ba[lane];
  const float ba1 = ba[lane + 64];
  const float bb0 = bb[lane];
  const int rowBase = blockIdx.x * rowsPerBlock;

  for (int rr = wave; rr < rowsPerBlock; rr += 4) {
    const int row = rowBase + rr;
    const float x0 = src0[(size_t)row * 64 + lane];
    float x1 = 0.0f;
    if constexpr (KIN == 128) x1 = src1[(size_t)row * 64 + lane];

    float h0 = ba0, h1 = ba1;
#pragma unroll
    for (int k = 0; k < 64; ++k) {
      const float xk = lane_bcast(x0, k);
      h0 = fmaf(xk, Wa_s[k * 128 + lane], h0);
      h1 = fmaf(xk, Wa_s[k * 128 + 64 + lane], h1);
    }
    if constexpr (KIN == 128) {
#pragma unroll
      for (int k = 0; k < 64; ++k) {
        const float xk = lane_bcast(x1, k);
        h0 = fmaf(xk, Wa_s[(k + 64) * 128 + lane], h0);
        h1 = fmaf(xk, Wa_s[(k + 64) * 128 + 64 + lane], h1);
      }
    }
    h0 = fmaxf(h0, 0.0f);
    h1 = fmaxf(h1, 0.0f);

    float acc = bb0;
#pragma unroll
    for (int k = 0; k < 64; ++k) {
      const float hk = lane_bcast(h0, k);
      acc = fmaf(hk, Wb_s[k * 64 + lane], acc);
    }
#pragma unroll
    for (int k = 0; k < 64; ++k) {
      const float hk = lane_bcast(h1, k);
      acc = fmaf(hk, Wb_s[(k + 64) * 64 + lane], acc);
    }
    if constexpr (RESID) acc += x0;
    out[(size_t)row * 64 + lane] = acc;
  }
}

// One wave per agent. Positions for the batch staged in LDS (32 KB).
// Lane l holds message channel l of the running sum.
__global__ __launch_bounds__(256)
void agg_kernel(const float* __restrict__ pos,     // [B][N][2]
                const float* __restrict__ msgs,    // [B][N][64]
                const int* __restrict__ radius_ptr,
                float* __restrict__ agg,           // [B][N][64]
                int N, int agentsPerBlock)
{
  __shared__ float2 ps[4096];
  const int b = blockIdx.y;
  const float2* posb = (const float2*)(pos + (size_t)b * N * 2);
  for (int i = threadIdx.x; i < N; i += 256) ps[i] = posb[i];
  __syncthreads();

  const float r = (float)(*radius_ptr);
  const int lane = threadIdx.x & 63;
  const int wave = threadIdx.x >> 6;
  const int base = blockIdx.x * agentsPerBlock;
  const float* msgsb = msgs + (size_t)b * N * 64;

  for (int a = wave; a < agentsPerBlock; a += 4) {
    const int i = base + a;
    const float2 pi = ps[i];
    float acc = 0.0f;
    int count = 0;
    for (int c = 0; c < N; c += 64) {
      const int j = c + lane;
      const float2 pj = ps[j];
      const float dx = pi.x - pj.x;
      const float dy = pi.y - pj.y;
      const float d2 = __fmul_rn(dx, dx) + __fmul_rn(dy, dy);
      const bool ok = (sqrtf(d2) < r) && (j != i);
      unsigned long long mask = __ballot(ok);
      count += __popcll(mask);
      while (mask) {
        const int bit = __builtin_ctzll(mask);
        mask &= mask - 1;
        acc += msgsb[(size_t)(c + bit) * 64 + lane];
      }
    }
    const float deg = (float)(count > 0 ? count : 1);
    agg[((size_t)b * N + i) * 64 + lane] = acc / deg;
  }
}

extern "C" void kernel_launch(void* const* d_in, const int* in_sizes, int n_in,
                              void* d_out, int out_size, void* d_ws, size_t ws_size,
                              hipStream_t stream) {
  const float* states = (const float*)d_in[0];
  const float* pos    = (const float*)d_in[1];
  const int*   radius = (const int*)d_in[2];
  const float* W1 = (const float*)d_in[3];
  const float* b1 = (const float*)d_in[4];
  const float* W2 = (const float*)d_in[5];
  const float* b2 = (const float*)d_in[6];
  const float* W3 = (const float*)d_in[7];
  const float* b3 = (const float*)d_in[8];
  const float* W4 = (const float*)d_in[9];
  const float* b4 = (const float*)d_in[10];
  const float* W5 = (const float*)d_in[11];
  const float* b5 = (const float*)d_in[12];
  const float* W6 = (const float*)d_in[13];
  const float* b6 = (const float*)d_in[14];
  float* out = (float*)d_out;

  const int B = 4, N = 4096;
  const int ROWS = B * N;            // 16384
  float* msgs = (float*)d_ws;                      // 4 MB
  float* aggr = msgs + (size_t)ROWS * 64;          // 4 MB
  float* finalm = out;                             // reuse d_out for final_msgs

  // 1) messages = relu(X @ W1 + b1) @ W2 + b2
  mlp2_kernel<64, false><<<256, 256, 0, stream>>>(
      states, nullptr, W1, b1, W2, b2, msgs, ROWS / 256);

  // 2) aggregated = row-normalized adjacency @ messages
  agg_kernel<<<dim3(64, B), 256, 0, stream>>>(
      pos, msgs, radius, aggr, N, N / 64);

  // 3) final_msgs = relu([msgs, agg] @ W3 + b3) @ W4 + b4
  mlp2_kernel<128, false><<<256, 256, 0, stream>>>(
      msgs, aggr, W3, b3, W4, b4, finalm, ROWS / 256);

  // 4) out = states + relu([states, final_msgs] @ W5 + b5) @ W6 + b6
  mlp2_kernel<128, true><<<256, 256, 0, stream>>>(
      states, finalm, W5, b5, W6, b6, out, ROWS / 256);
}

// Round 2
// 69.613 us; speedup vs baseline: 6.2492x; 6.2492x over previous
//
#include <hip/hip_runtime.h>

typedef unsigned short u16;
typedef __bf16 bf16x8 __attribute__((ext_vector_type(8)));
typedef unsigned short ushort8 __attribute__((ext_vector_type(8)));
typedef float f32x4 __attribute__((ext_vector_type(4)));

#define DEV_INLINE __device__ __forceinline__

constexpr int NB = 4;        // batches
constexpr int NAG = 4096;    // agents per batch
constexpr int ROWS = NB * NAG;

DEV_INLINE u16 f2bu(float x) { __bf16 h = (__bf16)x; return __builtin_bit_cast(u16, h); }
DEV_INLINE float bu2f(u16 u) { return __builtin_bit_cast(float, ((unsigned)u) << 16); }

// ---------------- weight prep: transpose fp32 W -> bf16 W^T ----------------
// layout in wts (u16 elems): W1T[128][64] @0, W2T[64][128] @8192, W3T[128][128] @16384,
// W4T[64][128] @32768, W5T[128][128] @40960, W6T[64][128] @57344. total 65536.
__global__ __launch_bounds__(256) void prep_weights(
    const float* __restrict__ W1, const float* __restrict__ W2,
    const float* __restrict__ W3, const float* __restrict__ W4,
    const float* __restrict__ W5, const float* __restrict__ W6,
    u16* __restrict__ out)
{
  const int idx = blockIdx.x * 256 + threadIdx.x;   // 0..65535
  const float* src; int n, k, Nc;
  if (idx < 8192)       { src = W1; int li = idx;          n = li >> 6; k = li & 63;  Nc = 128; }
  else if (idx < 16384) { src = W2; int li = idx - 8192;   n = li >> 7; k = li & 127; Nc = 64;  }
  else if (idx < 32768) { src = W3; int li = idx - 16384;  n = li >> 7; k = li & 127; Nc = 128; }
  else if (idx < 40960) { src = W4; int li = idx - 32768;  n = li >> 7; k = li & 127; Nc = 64;  }
  else if (idx < 57344) { src = W5; int li = idx - 40960;  n = li >> 7; k = li & 127; Nc = 128; }
  else                  { src = W6; int li = idx - 57344;  n = li >> 7; k = li & 127; Nc = 64;  }
  out[idx] = f2bu(src[k * Nc + n]);
}

// ---------------- fused 2-layer MLP via bf16 MFMA ----------------
// y = relu(x @ Wa + ba) @ Wb + bb (+resid). x: [ROWS][KIN] from 1-2 sources of 64 cols.
// Each wave: 16 rows. A-frag: lane reads x[rb+(l&15)][kt*32+(l>>4)*8 .. +8].
// B-frag from W^T in LDS: lane reads WT[(nt*16+(l&15))][kt*32+(l>>4)*8 .. +8].
// C layout: col = l&15, row = (l>>4)*4 + r  (verified layout).
template<bool BF>
DEV_INLINE bf16x8 loadA(const void* __restrict__ src, int row, int c) {
  if constexpr (BF) {
    ushort8 u = *reinterpret_cast<const ushort8*>((const u16*)src + (size_t)row * 64 + c);
    return __builtin_bit_cast(bf16x8, u);
  } else {
    const float* f = (const float*)src + (size_t)row * 64 + c;
    f32x4 a = *(const f32x4*)f;
    f32x4 b = *(const f32x4*)(f + 4);
    bf16x8 r;
    r[0] = (__bf16)a[0]; r[1] = (__bf16)a[1]; r[2] = (__bf16)a[2]; r[3] = (__bf16)a[3];
    r[4] = (__bf16)b[0]; r[5] = (__bf16)b[1]; r[6] = (__bf16)b[2]; r[7] = (__bf16)b[3];
    return r;
  }
}

template<int KIN, bool A0BF, bool A1BF, bool RESID, bool OUTBF>
__global__ __launch_bounds__(256) void mlp_mfma(
    const void* __restrict__ src0, const void* __restrict__ src1,
    const u16* __restrict__ WaT, const u16* __restrict__ WbT,
    const float* __restrict__ ba, const float* __restrict__ bb,
    const float* __restrict__ resid, void* __restrict__ dst)
{
  constexpr int KP = KIN + 8;            // padded row (stride = KP*2 B, == 4 mod 32 dwords)
  extern __shared__ u16 smem[];
  u16* WaTs = smem;                      // [128][KP]
  u16* WbTs = smem + 128 * KP;           // [64][136]
  const int lane = threadIdx.x & 63;
  const int wave = threadIdx.x >> 6;
  u16* hs = WbTs + 64 * 136 + wave * (16 * 136);   // per-wave hidden [16][136]

  for (int t = threadIdx.x; t < (128 * KIN) / 8; t += 256) {
    int e = t * 8; int n = e / KIN; int k = e - n * KIN;
    *(ushort8*)&WaTs[n * KP + k] = *(const ushort8*)&WaT[e];
  }
  for (int t = threadIdx.x; t < 1024; t += 256) {
    int e = t * 8; int n = e >> 7; int k = e & 127;
    *(ushort8*)&WbTs[n * 136 + k] = *(const ushort8*)&WbT[e];
  }
  __syncthreads();

  const int l15 = lane & 15;
  const int khalf = (lane >> 4) * 8;
  const int rb = blockIdx.x * 64 + wave * 16;
  const int row = rb + l15;

  // GEMM1: h[16][128]
  f32x4 acc1[8] = {};
#pragma unroll
  for (int kt = 0; kt < KIN / 32; ++kt) {
    const int cc = (kt & 1) * 32 + khalf;
    bf16x8 a;
    if constexpr (KIN == 128) {
      if (kt >= 2) a = loadA<A1BF>(src1, row, cc);
      else         a = loadA<A0BF>(src0, row, cc);
    } else {
      a = loadA<A0BF>(src0, row, cc);
    }
#pragma unroll
    for (int nt = 0; nt < 8; ++nt) {
      ushort8 bu = *(const ushort8*)&WaTs[(nt * 16 + l15) * KP + kt * 32 + khalf];
      acc1[nt] = __builtin_amdgcn_mfma_f32_16x16x32_bf16(
          a, __builtin_bit_cast(bf16x8, bu), acc1[nt], 0, 0, 0);
    }
  }

  // bias + relu -> bf16 -> per-wave LDS tile [m][k]
#pragma unroll
  for (int nt = 0; nt < 8; ++nt) {
    const float bav = ba[nt * 16 + l15];
#pragma unroll
    for (int r = 0; r < 4; ++r) {
      float v = acc1[nt][r] + bav;
      v = fmaxf(v, 0.0f);
      hs[((lane >> 4) * 4 + r) * 136 + nt * 16 + l15] = f2bu(v);
    }
  }

  // GEMM2: out[16][64]
  f32x4 acc2[4] = {};
#pragma unroll
  for (int kt = 0; kt < 4; ++kt) {
    ushort8 au = *(const ushort8*)&hs[l15 * 136 + kt * 32 + khalf];
    bf16x8 a2 = __builtin_bit_cast(bf16x8, au);
#pragma unroll
    for (int nt = 0; nt < 4; ++nt) {
      ushort8 bu = *(const ushort8*)&WbTs[(nt * 16 + l15) * 136 + kt * 32 + khalf];
      acc2[nt] = __builtin_amdgcn_mfma_f32_16x16x32_bf16(
          a2, __builtin_bit_cast(bf16x8, bu), acc2[nt], 0, 0, 0);
    }
  }

#pragma unroll
  for (int nt = 0; nt < 4; ++nt) {
    const int gc = nt * 16 + l15;
    const float bbv = bb[gc];
#pragma unroll
    for (int r = 0; r < 4; ++r) {
      const int m = (lane >> 4) * 4 + r;
      const size_t o = (size_t)(rb + m) * 64 + gc;
      float v = acc2[nt][r] + bbv;
      if constexpr (RESID) v += resid[o];
      if constexpr (OUTBF) ((u16*)dst)[o] = f2bu(v);
      else                 ((float*)dst)[o] = v;
    }
  }
}

// ---------------- neighbor aggregation ----------------
// Per wave: 4 agents. Phase 1: scan 64-candidate chunks, ballot-compact neighbor
// indices into LDS (no serial loads). Phase 2: gather messages in batches of 8
// independent loads; mean; store bf16.
__global__ __launch_bounds__(256) void agg_kernel(
    const float* __restrict__ pos, const u16* __restrict__ msgs,
    const int* __restrict__ radius_ptr, u16* __restrict__ aggr)
{
  __shared__ float2 ps[NAG];
  __shared__ u16 idxb[4][4][96];
  const int b = blockIdx.y;
  {
    const float4* p4 = (const float4*)(pos + (size_t)b * NAG * 2);
    float4* s4 = (float4*)ps;
    for (int t = threadIdx.x; t < NAG / 2; t += 256) s4[t] = p4[t];
  }
  __syncthreads();

  const float r = (float)(*radius_ptr);
  const float r2 = r * r;
  const int lane = threadIdx.x & 63;
  const int wave = threadIdx.x >> 6;
  const int i0 = blockIdx.x * 16 + wave * 4;
  const unsigned long long lt = (1ull << lane) - 1ull;

  float2 pi[4];
  int cnt[4];
#pragma unroll
  for (int a = 0; a < 4; ++a) { pi[a] = ps[i0 + a]; cnt[a] = 0; }

  for (int c = 0; c < NAG; c += 64) {
    const int j = c + lane;
    const float2 pj = ps[j];
#pragma unroll
    for (int a = 0; a < 4; ++a) {
      const float dx = pi[a].x - pj.x;
      const float dy = pi[a].y - pj.y;
      const float d2 = __fmul_rn(dx, dx) + __fmul_rn(dy, dy);
      const bool ok = (d2 < r2) && (j != i0 + a);
      const unsigned long long m = __ballot(ok);
      if (ok) idxb[wave][a][cnt[a] + __popcll(m & lt)] = (u16)j;
      cnt[a] += (int)__popcll(m);
    }
  }

  const u16* mb = msgs + (size_t)b * NAG * 64;
#pragma unroll
  for (int a = 0; a < 4; ++a) {
    const int n = cnt[a];
    const float inv = 1.0f / (float)(n > 0 ? n : 1);
    float acc = 0.0f;
    for (int g = 0; g < n; g += 8) {
      float vs[8];
#pragma unroll
      for (int s = 0; s < 8; ++s) {
        const int p = g + s;
        const int jj = idxb[wave][a][p < n ? p : 0];
        vs[s] = bu2f(mb[(size_t)jj * 64 + lane]);
      }
#pragma unroll
      for (int s = 0; s < 8; ++s) acc += (g + s < n) ? vs[s] : 0.0f;
    }
    aggr[((size_t)b * NAG + i0 + a) * 64 + lane] = f2bu(acc * inv);
  }
}

// ---------------- launch ----------------
extern "C" void kernel_launch(void* const* d_in, const int* in_sizes, int n_in,
                              void* d_out, int out_size, void* d_ws, size_t ws_size,
                              hipStream_t stream) {
  const float* states = (const float*)d_in[0];
  const float* pos    = (const float*)d_in[1];
  const int*   radius = (const int*)d_in[2];
  const float* W1 = (const float*)d_in[3];
  const float* b1 = (const float*)d_in[4];
  const float* W2 = (const float*)d_in[5];
  const float* b2 = (const float*)d_in[6];
  const float* W3 = (const float*)d_in[7];
  const float* b3 = (const float*)d_in[8];
  const float* W4 = (const float*)d_in[9];
  const float* b4 = (const float*)d_in[10];
  const float* W5 = (const float*)d_in[11];
  const float* b5 = (const float*)d_in[12];
  const float* W6 = (const float*)d_in[13];
  const float* b6 = (const float*)d_in[14];
  float* out = (float*)d_out;

  u16* ws16   = (u16*)d_ws;
  u16* msgs   = ws16;                       // [ROWS][64] bf16
  u16* aggr   = msgs + (size_t)ROWS * 64;   // [ROWS][64] bf16
  u16* finalm = aggr + (size_t)ROWS * 64;   // [ROWS][64] bf16
  u16* wts    = finalm + (size_t)ROWS * 64; // 65536 bf16 transposed weights

  constexpr int LDS64  = (128 * 72  + 64 * 136 + 4 * 16 * 136) * 2;  // 53248
  constexpr int LDS128 = (128 * 136 + 64 * 136 + 4 * 16 * 136) * 2;  // 69632

  prep_weights<<<256, 256, 0, stream>>>(W1, W2, W3, W4, W5, W6, wts);

  // 1) messages = relu(states@W1+b1)@W2+b2  -> bf16
  mlp_mfma<64, false, false, false, true><<<256, 256, LDS64, stream>>>(
      states, nullptr, wts + 0, wts + 8192, b1, b2, nullptr, msgs);

  // 2) aggregated = mean of neighbor messages -> bf16
  agg_kernel<<<dim3(256, NB), 256, 0, stream>>>(pos, msgs, radius, aggr);

  // 3) final = relu([msgs,agg]@W3+b3)@W4+b4 -> bf16
  mlp_mfma<128, true, true, false, true><<<256, 256, LDS128, stream>>>(
      msgs, aggr, wts + 16384, wts + 32768, b3, b4, nullptr, finalm);

  // 4) out = states + relu([states,final]@W5+b5)@W6+b6 -> fp32
  mlp_mfma<128, false, true, true, false><<<256, 256, LDS128, stream>>>(
      states, finalm, wts + 40960, wts + 57344, b5, b6, states, out);
}

// Round 3
// 50.032 us; speedup vs baseline: 8.6949x; 1.3914x over previous
//
#include <hip/hip_runtime.h>

typedef unsigned short u16;
typedef __bf16 bf16x8 __attribute__((ext_vector_type(8)));
typedef unsigned short ushort8 __attribute__((ext_vector_type(8)));
typedef float f32x4 __attribute__((ext_vector_type(4)));

#define DEV_INLINE __device__ __forceinline__

constexpr int NB = 4;        // batches
constexpr int NAG = 4096;    // agents per batch
constexpr int ROWS = NB * NAG;
constexpr int GRID = 20;     // bin grid (cell size 1.0 >= radius)
constexpr int CELLS = GRID * GRID;
constexpr int CSTRIDE = 404; // padded (CELLS+1)
constexpr int MAXNB = 320;   // per-agent neighbor index cap (λ≈32, ultra-safe)

DEV_INLINE u16 f2bu(float x) { __bf16 h = (__bf16)x; return __builtin_bit_cast(u16, h); }
DEV_INLINE float bu2f(u16 u) { return __builtin_bit_cast(float, ((unsigned)u) << 16); }

// ---------------- setup: binning (blocks 0..3) + weight transpose (blocks 4..67) ---
// wts layout (u16): W1T[128][64]@0, W2T[64][128]@8192, W3T[128][128]@16384,
// W4T[64][128]@32768, W5T[128][128]@40960, W6T[64][128]@57344.
__global__ __launch_bounds__(1024) void setup_kernel(
    const float* __restrict__ pos,
    const float* __restrict__ W1, const float* __restrict__ W2,
    const float* __restrict__ W3, const float* __restrict__ W4,
    const float* __restrict__ W5, const float* __restrict__ W6,
    u16* __restrict__ wts, float2* __restrict__ pos_sorted,
    int* __restrict__ cell_start, int* __restrict__ sid, int* __restrict__ invp)
{
  if (blockIdx.x >= NB) {
    const int idx = (blockIdx.x - NB) * 1024 + threadIdx.x;   // 0..65535
    const float* src; int n, k, Nc;
    if (idx < 8192)       { src = W1; int li = idx;          n = li >> 6; k = li & 63;  Nc = 128; }
    else if (idx < 16384) { src = W2; int li = idx - 8192;   n = li >> 7; k = li & 127; Nc = 64;  }
    else if (idx < 32768) { src = W3; int li = idx - 16384;  n = li >> 7; k = li & 127; Nc = 128; }
    else if (idx < 40960) { src = W4; int li = idx - 32768;  n = li >> 7; k = li & 127; Nc = 64;  }
    else if (idx < 57344) { src = W5; int li = idx - 40960;  n = li >> 7; k = li & 127; Nc = 128; }
    else                  { src = W6; int li = idx - 57344;  n = li >> 7; k = li & 127; Nc = 64;  }
    wts[idx] = f2bu(src[k * Nc + n]);
    return;
  }

  __shared__ int cnt_s[CELLS];
  __shared__ int start_s[CELLS + 1];
  __shared__ int scan_s[512];
  __shared__ u16 cell_of[NAG];
  __shared__ u16 rank_of[NAG];

  const int b = blockIdx.x;
  const float2* pb = (const float2*)(pos + (size_t)b * NAG * 2);
  for (int c = threadIdx.x; c < CELLS; c += 1024) cnt_s[c] = 0;
  __syncthreads();

  for (int i = threadIdx.x; i < NAG; i += 1024) {
    float2 p = pb[i];
    int cx = min(max((int)floorf(p.x), 0), GRID - 1);
    int cy = min(max((int)floorf(p.y), 0), GRID - 1);
    int c = cy * GRID + cx;
    int rk = atomicAdd(&cnt_s[c], 1);
    cell_of[i] = (u16)c;
    rank_of[i] = (u16)rk;
  }
  __syncthreads();

  // Hillis-Steele inclusive scan over 512 (CELLS padded)
  if (threadIdx.x < 512) scan_s[threadIdx.x] = (threadIdx.x < CELLS) ? cnt_s[threadIdx.x] : 0;
  __syncthreads();
  for (int off = 1; off < 512; off <<= 1) {
    int x = 0;
    if (threadIdx.x < 512) {
      x = scan_s[threadIdx.x];
      if (threadIdx.x >= off) x += scan_s[threadIdx.x - off];
    }
    __syncthreads();
    if (threadIdx.x < 512) scan_s[threadIdx.x] = x;
    __syncthreads();
  }
  if (threadIdx.x <= CELLS) {
    int st = (threadIdx.x == 0) ? 0 : scan_s[threadIdx.x - 1];
    start_s[threadIdx.x] = st;
    cell_start[b * CSTRIDE + threadIdx.x] = st;
  }
  __syncthreads();

  for (int i = threadIdx.x; i < NAG; i += 1024) {
    int k = start_s[cell_of[i]] + rank_of[i];
    sid[b * NAG + k]  = b * NAG + i;   // sorted -> original (global rows)
    invp[b * NAG + i] = b * NAG + k;   // original -> sorted (global rows)
    pos_sorted[b * NAG + k] = pb[i];
  }
}

// ---------------- fused 2-layer MLP via bf16 MFMA ----------------
template<bool BF>
DEV_INLINE bf16x8 loadA(const void* __restrict__ src, int row, int c) {
  if constexpr (BF) {
    ushort8 u = *reinterpret_cast<const ushort8*>((const u16*)src + (size_t)row * 64 + c);
    return __builtin_bit_cast(bf16x8, u);
  } else {
    const float* f = (const float*)src + (size_t)row * 64 + c;
    f32x4 a = *(const f32x4*)f;
    f32x4 b = *(const f32x4*)(f + 4);
    bf16x8 r;
    r[0] = (__bf16)a[0]; r[1] = (__bf16)a[1]; r[2] = (__bf16)a[2]; r[3] = (__bf16)a[3];
    r[4] = (__bf16)b[0]; r[5] = (__bf16)b[1]; r[6] = (__bf16)b[2]; r[7] = (__bf16)b[3];
    return r;
  }
}

template<int KIN, bool A0BF, bool A1BF, bool RESID, bool OUTBF, bool PERM>
__global__ __launch_bounds__(256) void mlp_mfma(
    const void* __restrict__ src0, const void* __restrict__ src1,
    const u16* __restrict__ WaT, const u16* __restrict__ WbT,
    const float* __restrict__ ba, const float* __restrict__ bb,
    const float* __restrict__ resid, const int* __restrict__ perm,
    void* __restrict__ dst)
{
  constexpr int KP = KIN + 8;
  extern __shared__ u16 smem[];
  u16* WaTs = smem;                      // [128][KP]
  u16* WbTs = smem + 128 * KP;           // [64][136]
  const int lane = threadIdx.x & 63;
  const int wave = threadIdx.x >> 6;
  u16* hs = WbTs + 64 * 136 + wave * (16 * 136);   // per-wave hidden [16][136]

  for (int t = threadIdx.x; t < (128 * KIN) / 8; t += 256) {
    int e = t * 8; int n = e / KIN; int k = e - n * KIN;
    *(ushort8*)&WaTs[n * KP + k] = *(const ushort8*)&WaT[e];
  }
  for (int t = threadIdx.x; t < 1024; t += 256) {
    int e = t * 8; int n = e >> 7; int k = e & 127;
    *(ushort8*)&WbTs[n * 136 + k] = *(const ushort8*)&WbT[e];
  }
  __syncthreads();

  const int l15 = lane & 15;
  const int khalf = (lane >> 4) * 8;
  const int rb = blockIdx.x * 64 + wave * 16;
  const int row = rb + l15;

  f32x4 acc1[8] = {};
#pragma unroll
  for (int kt = 0; kt < KIN / 32; ++kt) {
    const int cc = (kt & 1) * 32 + khalf;
    bf16x8 a;
    if constexpr (KIN == 128) {
      if (kt >= 2) a = loadA<A1BF>(src1, row, cc);
      else         a = loadA<A0BF>(src0, row, cc);
    } else {
      a = loadA<A0BF>(src0, row, cc);
    }
#pragma unroll
    for (int nt = 0; nt < 8; ++nt) {
      ushort8 bu = *(const ushort8*)&WaTs[(nt * 16 + l15) * KP + kt * 32 + khalf];
      acc1[nt] = __builtin_amdgcn_mfma_f32_16x16x32_bf16(
          a, __builtin_bit_cast(bf16x8, bu), acc1[nt], 0, 0, 0);
    }
  }

#pragma unroll
  for (int nt = 0; nt < 8; ++nt) {
    const float bav = ba[nt * 16 + l15];
#pragma unroll
    for (int r = 0; r < 4; ++r) {
      float v = acc1[nt][r] + bav;
      v = fmaxf(v, 0.0f);
      hs[((lane >> 4) * 4 + r) * 136 + nt * 16 + l15] = f2bu(v);
    }
  }

  f32x4 acc2[4] = {};
#pragma unroll
  for (int kt = 0; kt < 4; ++kt) {
    ushort8 au = *(const ushort8*)&hs[l15 * 136 + kt * 32 + khalf];
    bf16x8 a2 = __builtin_bit_cast(bf16x8, au);
#pragma unroll
    for (int nt = 0; nt < 4; ++nt) {
      ushort8 bu = *(const ushort8*)&WbTs[(nt * 16 + l15) * 136 + kt * 32 + khalf];
      acc2[nt] = __builtin_amdgcn_mfma_f32_16x16x32_bf16(
          a2, __builtin_bit_cast(bf16x8, bu), acc2[nt], 0, 0, 0);
    }
  }

  int drow[4];
#pragma unroll
  for (int r = 0; r < 4; ++r) {
    const int orow = rb + (lane >> 4) * 4 + r;
    drow[r] = PERM ? perm[orow] : orow;
  }

#pragma unroll
  for (int nt = 0; nt < 4; ++nt) {
    const int gc = nt * 16 + l15;
    const float bbv = bb[gc];
#pragma unroll
    for (int r = 0; r < 4; ++r) {
      const int m = (lane >> 4) * 4 + r;
      const size_t o = (size_t)drow[r] * 64 + gc;
      float v = acc2[nt][r] + bbv;
      if constexpr (RESID) v += resid[(size_t)(rb + m) * 64 + gc];
      if constexpr (OUTBF) ((u16*)dst)[o] = f2bu(v);
      else                 ((float*)dst)[o] = v;
    }
  }
}

// ---------------- aggregation in sorted space ----------------
// One wave per sorted agent k. Candidates = 3 contiguous ranges (3x3 cells).
// Mask phase: 64-wide ballot over coalesced position loads; compact to LDS.
// Gather phase: vector index fetch + 8 independent message-row loads.
__global__ __launch_bounds__(256) void agg_kernel(
    const float2* __restrict__ pos_sorted, const u16* __restrict__ msgs,
    const int* __restrict__ cell_start, const int* __restrict__ radius_ptr,
    u16* __restrict__ aggr)
{
  __shared__ u16 idxb[4][MAXNB];
  const int b = blockIdx.y;
  const int lane = threadIdx.x & 63;
  const int wave = threadIdx.x >> 6;
  const int k = blockIdx.x * 4 + wave;
  const float2* pb = pos_sorted + (size_t)b * NAG;
  const float2 pk = pb[k];
  const float r = (float)(*radius_ptr);
  const float r2 = __fmul_rn(r, r);
  const int cx = min(max((int)floorf(pk.x), 0), GRID - 1);
  const int cy = min(max((int)floorf(pk.y), 0), GRID - 1);
  const int* cs = cell_start + b * CSTRIDE;
  const unsigned long long lt = (1ull << lane) - 1ull;

  int cnt = 0;
#pragma unroll
  for (int dy = -1; dy <= 1; ++dy) {
    const int yy = cy + dy;
    if (yy < 0 || yy >= GRID) continue;
    const int x0 = max(cx - 1, 0), x1 = min(cx + 1, GRID - 1);
    const int c0 = cs[yy * GRID + x0];
    const int c1 = cs[yy * GRID + x1 + 1];
    for (int base = c0; base < c1; base += 64) {
      const int j = base + lane;
      bool ok = false;
      if (j < c1) {
        const float2 pj = pb[j];
        const float dx_ = pk.x - pj.x;
        const float dy_ = pk.y - pj.y;
        const float d2 = __fadd_rn(__fmul_rn(dx_, dx_), __fmul_rn(dy_, dy_));
        ok = (d2 < r2) && (j != k);
      }
      const unsigned long long m = __ballot(ok);
      if (ok) {
        const int p = cnt + __popcll(m & lt);
        if (p < MAXNB) idxb[wave][p] = (u16)j;
      }
      cnt += (int)__popcll(m);
    }
  }

  const u16* mb = msgs + (size_t)b * NAG * 64;
  float acc = 0.0f;
  const int n = min(cnt, MAXNB);
  for (int g = 0; g < n; g += 8) {
    ushort8 ii = *(const ushort8*)&idxb[wave][g];   // 16B-aligned (MAXNB%8==0)
    float vs[8];
#pragma unroll
    for (int s = 0; s < 8; ++s) {
      const int jj = (g + s < n) ? (int)ii[s] : (int)ii[0];
      vs[s] = bu2f(mb[(size_t)jj * 64 + lane]);
    }
#pragma unroll
    for (int s = 0; s < 8; ++s) acc += (g + s < n) ? vs[s] : 0.0f;
  }
  const float inv = 1.0f / (float)(cnt > 0 ? cnt : 1);
  aggr[((size_t)b * NAG + k) * 64 + lane] = f2bu(acc * inv);
}

// ---------------- launch ----------------
extern "C" void kernel_launch(void* const* d_in, const int* in_sizes, int n_in,
                              void* d_out, int out_size, void* d_ws, size_t ws_size,
                              hipStream_t stream) {
  const float* states = (const float*)d_in[0];
  const float* pos    = (const float*)d_in[1];
  const int*   radius = (const int*)d_in[2];
  const float* W1 = (const float*)d_in[3];
  const float* b1 = (const float*)d_in[4];
  const float* W2 = (const float*)d_in[5];
  const float* b2 = (const float*)d_in[6];
  const float* W3 = (const float*)d_in[7];
  const float* b3 = (const float*)d_in[8];
  const float* W4 = (const float*)d_in[9];
  const float* b4 = (const float*)d_in[10];
  const float* W5 = (const float*)d_in[11];
  const float* b5 = (const float*)d_in[12];
  const float* W6 = (const float*)d_in[13];
  const float* b6 = (const float*)d_in[14];
  float* out = (float*)d_out;

  u16* ws16   = (u16*)d_ws;
  u16* msgs   = ws16;                       // [ROWS][64] bf16, SORTED order
  u16* aggr   = msgs + (size_t)ROWS * 64;   // [ROWS][64] bf16, SORTED order
  u16* finalm = aggr + (size_t)ROWS * 64;   // [ROWS][64] bf16, ORIGINAL order
  u16* wts    = finalm + (size_t)ROWS * 64; // 65536 bf16 transposed weights
  char* pbyte = (char*)(wts + 65536);
  float2* pos_sorted = (float2*)pbyte;                       // ROWS float2
  int* cell_start = (int*)(pbyte + (size_t)ROWS * 8);        // NB*CSTRIDE
  int* sid  = cell_start + NB * CSTRIDE;                     // ROWS
  int* invp = sid + ROWS;                                    // ROWS

  constexpr int LDS64  = (128 * 72  + 64 * 136 + 4 * 16 * 136) * 2;  // 53248
  constexpr int LDS128 = (128 * 136 + 64 * 136 + 4 * 16 * 136) * 2;  // 69632

  // 0) binning + weight transpose
  setup_kernel<<<NB + 64, 1024, 0, stream>>>(
      pos, W1, W2, W3, W4, W5, W6, wts, pos_sorted, cell_start, sid, invp);

  // 1) messages = relu(states@W1+b1)@W2+b2 -> bf16, scatter to sorted order
  mlp_mfma<64, false, false, false, true, true><<<256, 256, LDS64, stream>>>(
      states, nullptr, wts + 0, wts + 8192, b1, b2, nullptr, invp, msgs);

  // 2) aggregated = mean of neighbor messages (sorted space) -> bf16
  agg_kernel<<<dim3(NAG / 4, NB), 256, 0, stream>>>(
      pos_sorted, msgs, cell_start, radius, aggr);

  // 3) final = relu([msgs,agg]@W3+b3)@W4+b4 -> bf16, scatter back to original order
  mlp_mfma<128, true, true, false, true, true><<<256, 256, LDS128, stream>>>(
      msgs, aggr, wts + 16384, wts + 32768, b3, b4, nullptr, sid, finalm);

  // 4) out = states + relu([states,final]@W5+b5)@W6+b6 -> fp32
  mlp_mfma<128, false, true, true, false, false><<<256, 256, LDS128, stream>>>(
      states, finalm, wts + 40960, wts + 57344, b5, b6, states, nullptr, out);
}

// Round 4
// 43.377 us; speedup vs baseline: 10.0290x; 1.1534x over previous
//
#include <hip/hip_runtime.h>

typedef unsigned short u16;
typedef __bf16 bf16x8 __attribute__((ext_vector_type(8)));
typedef unsigned short ushort8 __attribute__((ext_vector_type(8)));
typedef float f32x4 __attribute__((ext_vector_type(4)));

#define DEV_INLINE __device__ __forceinline__

constexpr int NB = 4;        // batches
constexpr int NAG = 4096;    // agents per batch
constexpr int ROWS = NB * NAG;
constexpr int GRID = 20;     // bin grid (cell size 1.0 >= radius)
constexpr int CELLS = GRID * GRID;
constexpr int CSTRIDE = 404;
constexpr int MAXNB = 320;   // per-agent neighbor cap (lambda ~32)

DEV_INLINE u16 f2bu(float x) { __bf16 h = (__bf16)x; return __builtin_bit_cast(u16, h); }
DEV_INLINE float bu2f(u16 u) { return __builtin_bit_cast(float, ((unsigned)u) << 16); }

DEV_INLINE f32x4 MF(bf16x8 a, const u16* p, f32x4 c) {
  ushort8 bu = *(const ushort8*)p;
  return __builtin_amdgcn_mfma_f32_16x16x32_bf16(a, __builtin_bit_cast(bf16x8, bu), c, 0, 0, 0);
}

template<bool BF>
DEV_INLINE bf16x8 loadA(const void* __restrict__ src, int row, int c) {
  if constexpr (BF) {
    ushort8 u = *reinterpret_cast<const ushort8*>((const u16*)src + (size_t)row * 64 + c);
    return __builtin_bit_cast(bf16x8, u);
  } else {
    const float* f = (const float*)src + (size_t)row * 64 + c;
    f32x4 a = *(const f32x4*)f;
    f32x4 b = *(const f32x4*)(f + 4);
    bf16x8 r;
    r[0] = (__bf16)a[0]; r[1] = (__bf16)a[1]; r[2] = (__bf16)a[2]; r[3] = (__bf16)a[3];
    r[4] = (__bf16)b[0]; r[5] = (__bf16)b[1]; r[6] = (__bf16)b[2]; r[7] = (__bf16)b[3];
    return r;
  }
}

// ================= K1: binning (blocks 0..3) | mlp1 (4..259) | W3-6 transpose (260..275)
// wts layout (u16): W3T[128n][128k]@0, W4T[64][128]@16384, W5T[128][128]@24576, W6T[64][128]@40960.
__global__ __launch_bounds__(256) void fused_setup_mlp1(
    const float* __restrict__ pos, const float* __restrict__ states,
    const float* __restrict__ W1, const float* __restrict__ b1,
    const float* __restrict__ W2, const float* __restrict__ b2,
    const float* __restrict__ W3, const float* __restrict__ W4,
    const float* __restrict__ W5, const float* __restrict__ W6,
    u16* __restrict__ wts, u16* __restrict__ msgs,
    float2* __restrict__ pos_sorted, int* __restrict__ cell_start,
    int* __restrict__ sid)
{
  extern __shared__ u16 smem[];
  const int tid = threadIdx.x;
  const int lane = tid & 63;
  const int wave = tid >> 6;

  if (blockIdx.x < NB) {
    // ---------- binning ----------
    int* cnt_s = (int*)smem;                       // [400]
    int* start_s = cnt_s + CELLS;                  // [401]
    u16* cell_of = (u16*)(start_s + CELLS + 1);    // [4096]
    u16* rank_of = cell_of + NAG;                  // [4096]
    const int b = blockIdx.x;
    const float2* pb = (const float2*)(pos + (size_t)b * NAG * 2);
    for (int c = tid; c < CELLS; c += 256) cnt_s[c] = 0;
    __syncthreads();
    for (int i = tid; i < NAG; i += 256) {
      float2 p = pb[i];
      int cx = min(max((int)floorf(p.x), 0), GRID - 1);
      int cy = min(max((int)floorf(p.y), 0), GRID - 1);
      int c = cy * GRID + cx;
      rank_of[i] = (u16)atomicAdd(&cnt_s[c], 1);
      cell_of[i] = (u16)c;
    }
    __syncthreads();
    if (wave == 0) {     // exclusive scan over 400 cells by wave 0
      int carry = 0;
      for (int g = 0; g < CELLS; g += 64) {
        int c = g + lane;
        int x = (c < CELLS) ? cnt_s[c] : 0;
#pragma unroll
        for (int off = 1; off < 64; off <<= 1) {
          int y = __shfl_up(x, off, 64);
          if (lane >= off) x += y;
        }
        if (c < CELLS) start_s[c + 1] = carry + x;
        carry += __shfl(x, 63, 64);
      }
      if (lane == 0) start_s[0] = 0;
    }
    __syncthreads();
    for (int c = tid; c <= CELLS; c += 256) cell_start[b * CSTRIDE + c] = start_s[c];
    for (int i = tid; i < NAG; i += 256) {
      int kk = start_s[cell_of[i]] + (int)rank_of[i];
      sid[b * NAG + kk] = b * NAG + i;
      pos_sorted[b * NAG + kk] = pb[i];
    }
    return;
  }

  if (blockIdx.x >= NB + 256) {
    // ---------- transpose W3..W6 -> bf16 wts ----------
    const int base = (blockIdx.x - (NB + 256)) * 3072;
#pragma unroll
    for (int t = 0; t < 12; ++t) {
      int idx = base + t * 256 + tid;                 // 0..49151
      const float* src; int n, k, Nc;
      if (idx < 16384)      { src = W3; n = idx >> 7; k = idx & 127; Nc = 128; }
      else if (idx < 24576) { int li = idx - 16384; src = W4; n = li >> 7; k = li & 127; Nc = 64; }
      else if (idx < 40960) { int li = idx - 24576; src = W5; n = li >> 7; k = li & 127; Nc = 128; }
      else                  { int li = idx - 40960; src = W6; n = li >> 7; k = li & 127; Nc = 64; }
      wts[idx] = f2bu(src[k * Nc + n]);
    }
    return;
  }

  // ---------- mlp1: msgs = relu(states@W1+b1)@W2+b2, orig order ----------
  u16* WaTs = smem;                      // [128][72]
  u16* WbTs = smem + 128 * 72;           // [64][136]
  u16* hs = WbTs + 64 * 136 + wave * (16 * 136);   // per-wave [16][136]

  for (int e = tid; e < 64 * 128; e += 256) {      // W1 fp32 [64k][128n] -> WaTs[n][k]
    int n = e & 127, k = e >> 7;
    WaTs[n * 72 + k] = f2bu(W1[e]);
  }
  for (int e = tid; e < 128 * 64; e += 256) {      // W2 fp32 [128k][64n] -> WbTs[n][k]
    int n = e & 63, k = e >> 6;
    WbTs[n * 136 + k] = f2bu(W2[e]);
  }
  __syncthreads();

  const int l15 = lane & 15;
  const int khalf = (lane >> 4) * 8;
  const int rb = (blockIdx.x - NB) * 64 + wave * 16;
  const int row = rb + l15;

  f32x4 acc1[8] = {};
#pragma unroll
  for (int kt = 0; kt < 2; ++kt) {
    bf16x8 a = loadA<false>(states, row, kt * 32 + khalf);
#pragma unroll
    for (int nt = 0; nt < 8; ++nt)
      acc1[nt] = MF(a, &WaTs[(nt * 16 + l15) * 72 + kt * 32 + khalf], acc1[nt]);
  }
#pragma unroll
  for (int nt = 0; nt < 8; ++nt) {
    const float bav = b1[nt * 16 + l15];
#pragma unroll
    for (int r = 0; r < 4; ++r)
      hs[((lane >> 4) * 4 + r) * 136 + nt * 16 + l15] = f2bu(fmaxf(acc1[nt][r] + bav, 0.0f));
  }
  f32x4 acc2[4] = {};
#pragma unroll
  for (int kt = 0; kt < 4; ++kt) {
    ushort8 au = *(const ushort8*)&hs[l15 * 136 + kt * 32 + khalf];
    bf16x8 a2 = __builtin_bit_cast(bf16x8, au);
#pragma unroll
    for (int nt = 0; nt < 4; ++nt)
      acc2[nt] = MF(a2, &WbTs[(nt * 16 + l15) * 136 + kt * 32 + khalf], acc2[nt]);
  }
#pragma unroll
  for (int nt = 0; nt < 4; ++nt) {
    const int gc = nt * 16 + l15;
    const float bbv = b2[gc];
#pragma unroll
    for (int r = 0; r < 4; ++r) {
      const int m = (lane >> 4) * 4 + r;
      msgs[(size_t)(rb + m) * 64 + gc] = f2bu(acc2[nt][r] + bbv);
    }
  }
}

// ================= K2: aggregation (sorted scan, orig-order gather/scatter via sid)
__global__ __launch_bounds__(256) void agg_kernel(
    const float2* __restrict__ pos_sorted, const u16* __restrict__ msgs,
    const int* __restrict__ cell_start, const int* __restrict__ sid,
    const int* __restrict__ radius_ptr, u16* __restrict__ aggr)
{
  __shared__ u16 idxb[4][MAXNB];
  const int b = blockIdx.y;
  const int lane = threadIdx.x & 63;
  const int wave = threadIdx.x >> 6;
  const int k = blockIdx.x * 4 + wave;
  const float2* pb = pos_sorted + (size_t)b * NAG;
  const float2 pk = pb[k];
  const float r = (float)(*radius_ptr);
  const float r2 = __fmul_rn(r, r);
  const int cx = min(max((int)floorf(pk.x), 0), GRID - 1);
  const int cy = min(max((int)floorf(pk.y), 0), GRID - 1);
  const int* cs = cell_start + b * CSTRIDE;
  const int* sb = sid + b * NAG;
  const unsigned long long lt = (1ull << lane) - 1ull;

  int cnt = 0;
#pragma unroll
  for (int dy = -1; dy <= 1; ++dy) {
    const int yy = cy + dy;
    if (yy < 0 || yy >= GRID) continue;
    const int x0 = max(cx - 1, 0), x1 = min(cx + 1, GRID - 1);
    const int c0 = cs[yy * GRID + x0];
    const int c1 = cs[yy * GRID + x1 + 1];
    for (int base = c0; base < c1; base += 64) {
      const int j = base + lane;
      bool ok = false;
      if (j < c1) {
        const float2 pj = pb[j];
        const float dx_ = pk.x - pj.x;
        const float dy_ = pk.y - pj.y;
        const float d2 = __fadd_rn(__fmul_rn(dx_, dx_), __fmul_rn(dy_, dy_));
        ok = (d2 < r2) && (j != k);
      }
      const unsigned long long m = __ballot(ok);
      if (ok) {
        const int p = cnt + __popcll(m & lt);
        if (p < MAXNB) idxb[wave][p] = (u16)sb[j];   // store ORIGINAL global row
      }
      cnt += (int)__popcll(m);
    }
  }

  float acc = 0.0f;
  const int n = min(cnt, MAXNB);
  for (int g = 0; g < n; g += 8) {
    ushort8 ii = *(const ushort8*)&idxb[wave][g];
    float vs[8];
#pragma unroll
    for (int s = 0; s < 8; ++s) {
      const int jj = (g + s < n) ? (int)ii[s] : (int)ii[0];
      vs[s] = bu2f(msgs[(size_t)jj * 64 + lane]);
    }
#pragma unroll
    for (int s = 0; s < 8; ++s) acc += (g + s < n) ? vs[s] : 0.0f;
  }
  const float inv = 1.0f / (float)(cnt > 0 ? cnt : 1);
  const int orow = sb[k];
  aggr[(size_t)orow * 64 + lane] = f2bu(acc * inv);
}

// ================= K3: fused MLP2+MLP3, all orig-order coalesced
__global__ __launch_bounds__(256) void mlp23_kernel(
    const float* __restrict__ states, const u16* __restrict__ msgs,
    const u16* __restrict__ aggr, const u16* __restrict__ wts,
    const float* __restrict__ b3, const float* __restrict__ b4,
    const float* __restrict__ b5, const float* __restrict__ b6,
    float* __restrict__ out)
{
  extern __shared__ u16 smem[];
  u16* W3s = smem;                 // [128][136]
  u16* W4s = W3s + 128 * 136;      // [64][136]
  u16* W5s = W4s + 64 * 136;       // [128][136]
  u16* W6s = W5s + 128 * 136;      // [64][136]
  const int tid = threadIdx.x;
  const int lane = tid & 63;
  const int wave = tid >> 6;
  u16* hs = W6s + 64 * 136 + wave * (2 * 16 * 136);  // per-wave hidden [16][136]
  u16* fs = hs + 16 * 136;                           // per-wave final  [16][136]

  for (int t = tid; t < 2048; t += 256) { int e = t * 8; int n = e >> 7, k = e & 127;
    *(ushort8*)&W3s[n * 136 + k] = *(const ushort8*)&wts[e]; }
  for (int t = tid; t < 1024; t += 256) { int e = t * 8; int n = e >> 7, k = e & 127;
    *(ushort8*)&W4s[n * 136 + k] = *(const ushort8*)&wts[16384 + e]; }
  for (int t = tid; t < 2048; t += 256) { int e = t * 8; int n = e >> 7, k = e & 127;
    *(ushort8*)&W5s[n * 136 + k] = *(const ushort8*)&wts[24576 + e]; }
  for (int t = tid; t < 1024; t += 256) { int e = t * 8; int n = e >> 7, k = e & 127;
    *(ushort8*)&W6s[n * 136 + k] = *(const ushort8*)&wts[40960 + e]; }
  __syncthreads();

  const int l15 = lane & 15;
  const int khalf = (lane >> 4) * 8;
  const int rb = blockIdx.x * 64 + wave * 16;
  const int row = rb + l15;

  // ---- MLP2 GEMM1: h = relu([msgs|aggr] @ W3 + b3) ----
  f32x4 acc1[8] = {};
#pragma unroll
  for (int kt = 0; kt < 4; ++kt) {
    const int cc = (kt & 1) * 32 + khalf;
    bf16x8 a = (kt < 2) ? loadA<true>(msgs, row, cc) : loadA<true>(aggr, row, cc);
#pragma unroll
    for (int nt = 0; nt < 8; ++nt)
      acc1[nt] = MF(a, &W3s[(nt * 16 + l15) * 136 + kt * 32 + khalf], acc1[nt]);
  }
#pragma unroll
  for (int nt = 0; nt < 8; ++nt) {
    const float bv = b3[nt * 16 + l15];
#pragma unroll
    for (int r = 0; r < 4; ++r)
      hs[((lane >> 4) * 4 + r) * 136 + nt * 16 + l15] = f2bu(fmaxf(acc1[nt][r] + bv, 0.0f));
  }
  // ---- MLP2 GEMM2: final = h @ W4 + b4 -> fs ----
  f32x4 acc2[4] = {};
#pragma unroll
  for (int kt = 0; kt < 4; ++kt) {
    ushort8 au = *(const ushort8*)&hs[l15 * 136 + kt * 32 + khalf];
    bf16x8 a2 = __builtin_bit_cast(bf16x8, au);
#pragma unroll
    for (int nt = 0; nt < 4; ++nt)
      acc2[nt] = MF(a2, &W4s[(nt * 16 + l15) * 136 + kt * 32 + khalf], acc2[nt]);
  }
#pragma unroll
  for (int nt = 0; nt < 4; ++nt) {
    const int gc = nt * 16 + l15;
    const float bv = b4[gc];
#pragma unroll
    for (int r = 0; r < 4; ++r)
      fs[((lane >> 4) * 4 + r) * 136 + gc] = f2bu(acc2[nt][r] + bv);
  }
  // ---- MLP3 GEMM1: h2 = relu([states|final] @ W5 + b5) ----
  f32x4 acc3[8] = {};
#pragma unroll
  for (int kt = 0; kt < 4; ++kt) {
    const int cc = (kt & 1) * 32 + khalf;
    bf16x8 a;
    if (kt < 2) a = loadA<false>(states, row, cc);
    else {
      ushort8 au = *(const ushort8*)&fs[l15 * 136 + cc];
      a = __builtin_bit_cast(bf16x8, au);
    }
#pragma unroll
    for (int nt = 0; nt < 8; ++nt)
      acc3[nt] = MF(a, &W5s[(nt * 16 + l15) * 136 + kt * 32 + khalf], acc3[nt]);
  }
#pragma unroll
  for (int nt = 0; nt < 8; ++nt) {
    const float bv = b5[nt * 16 + l15];
#pragma unroll
    for (int r = 0; r < 4; ++r)
      hs[((lane >> 4) * 4 + r) * 136 + nt * 16 + l15] = f2bu(fmaxf(acc3[nt][r] + bv, 0.0f));
  }
  // ---- MLP3 GEMM2 + residual ----
  f32x4 acc4[4] = {};
#pragma unroll
  for (int kt = 0; kt < 4; ++kt) {
    ushort8 au = *(const ushort8*)&hs[l15 * 136 + kt * 32 + khalf];
    bf16x8 a2 = __builtin_bit_cast(bf16x8, au);
#pragma unroll
    for (int nt = 0; nt < 4; ++nt)
      acc4[nt] = MF(a2, &W6s[(nt * 16 + l15) * 136 + kt * 32 + khalf], acc4[nt]);
  }
#pragma unroll
  for (int nt = 0; nt < 4; ++nt) {
    const int gc = nt * 16 + l15;
    const float bv = b6[gc];
#pragma unroll
    for (int r = 0; r < 4; ++r) {
      const int m = (lane >> 4) * 4 + r;
      const size_t o = (size_t)(rb + m) * 64 + gc;
      out[o] = acc4[nt][r] + bv + states[o];
    }
  }
}

// ================= launch
extern "C" void kernel_launch(void* const* d_in, const int* in_sizes, int n_in,
                              void* d_out, int out_size, void* d_ws, size_t ws_size,
                              hipStream_t stream) {
  const float* states = (const float*)d_in[0];
  const float* pos    = (const float*)d_in[1];
  const int*   radius = (const int*)d_in[2];
  const float* W1 = (const float*)d_in[3];
  const float* b1 = (const float*)d_in[4];
  const float* W2 = (const float*)d_in[5];
  const float* b2 = (const float*)d_in[6];
  const float* W3 = (const float*)d_in[7];
  const float* b3 = (const float*)d_in[8];
  const float* W4 = (const float*)d_in[9];
  const float* b4 = (const float*)d_in[10];
  const float* W5 = (const float*)d_in[11];
  const float* b5 = (const float*)d_in[12];
  const float* W6 = (const float*)d_in[13];
  const float* b6 = (const float*)d_in[14];
  float* out = (float*)d_out;

  u16* ws16 = (u16*)d_ws;
  u16* msgs = ws16;                         // [ROWS][64] bf16 (orig order)
  u16* aggr = msgs + (size_t)ROWS * 64;     // [ROWS][64] bf16 (orig order)
  u16* wts  = aggr + (size_t)ROWS * 64;     // 49152 bf16 W3T..W6T
  char* pbyte = (char*)(wts + 49152);
  float2* pos_sorted = (float2*)pbyte;                 // ROWS float2
  int* cell_start = (int*)(pbyte + (size_t)ROWS * 8);  // NB*CSTRIDE
  int* sid = cell_start + NB * CSTRIDE;                // ROWS

  constexpr int LDS_K1 = (128 * 72 + 64 * 136 + 4 * 16 * 136) * 2;                    // 53248
  constexpr int LDS_K3 = (128 * 136 + 64 * 136 + 128 * 136 + 64 * 136 + 4 * 2 * 16 * 136) * 2;  // 139264

  fused_setup_mlp1<<<NB + 256 + 16, 256, LDS_K1, stream>>>(
      pos, states, W1, b1, W2, b2, W3, W4, W5, W6,
      wts, msgs, pos_sorted, cell_start, sid);

  agg_kernel<<<dim3(NAG / 4, NB), 256, 0, stream>>>(
      pos_sorted, msgs, cell_start, sid, radius, aggr);

  mlp23_kernel<<<256, 256, LDS_K3, stream>>>(
      states, msgs, aggr, wts, b3, b4, b5, b6, out);
}